// Round 13
// baseline (138.196 us; speedup 1.0000x reference)
//
#include <hip/hip_runtime.h>
#include <math.h>

#define B_ 8
#define C_ 128
#define N_ 64
#define T_ 512
#define H_ 4
#define D_ 32
#define OUT_ 128
#define E_ 256
#define EP_ 320   // E + N self-loops
#define NEG_SLOPE 0.2f
#define BN_EPS 1e-5f
#define NT_ (N_ * T_)
#define TSTRIDE 136   // tile row stride in shorts (16B-aligned, bank-spread)

__device__ inline unsigned short f2bf(float f) {   // RNE float->bf16
  unsigned u = __float_as_uint(f);
  u += 0x7FFFu + ((u >> 16) & 1u);
  return (unsigned short)(u >> 16);
}
__device__ inline float bf2f(unsigned short s) {
  return __uint_as_float(((unsigned)s) << 16);
}

// ---- setup: wa[c][8] = W·att; in-list (src per in-edge, grouped by dst);
// ----        out-list (dst per out-edge, grouped by src)
__global__ void setup_kernel(const float* __restrict__ W,
                             const float* __restrict__ att_src,
                             const float* __restrict__ att_dst,
                             const int* __restrict__ edge_index,
                             float* __restrict__ wa,
                             int* __restrict__ iOff_g, int* __restrict__ iSrc_g,
                             int* __restrict__ oOff_g, int* __restrict__ oDst_g) {
  __shared__ int icnt[N_], ibase[N_ + 1], ifill[N_];
  __shared__ int ocnt[N_], obase[N_ + 1], ofill[N_];
  __shared__ int esrc[EP_], edst[EP_];
  int tid = threadIdx.x;

  for (int idx = tid; idx < C_ * 8; idx += blockDim.x) {
    int c = idx >> 3, j = idx & 7, h = j & 3;
    const float* att = (j < 4) ? att_src : att_dst;
    float s = 0.f;
    for (int d = 0; d < D_; ++d)
      s += W[(c * H_ + h) * D_ + d] * att[h * D_ + d];
    wa[idx] = s;
  }
  if (tid < N_) { icnt[tid] = 0; ifill[tid] = 0; ocnt[tid] = 0; ofill[tid] = 0; }
  __syncthreads();
  for (int e = tid; e < EP_; e += blockDim.x) {
    int s, d;
    if (e < E_) { s = edge_index[e]; d = edge_index[E_ + e]; }
    else        { s = e - E_;        d = e - E_; }
    esrc[e] = s; edst[e] = d;
    atomicAdd(&icnt[d], 1);
    atomicAdd(&ocnt[s], 1);
  }
  __syncthreads();
  if (tid == 0) {
    int ai = 0, ao = 0;
    for (int n = 0; n < N_; ++n) {
      ibase[n] = ai; ai += icnt[n];
      obase[n] = ao; ao += ocnt[n];
    }
    ibase[N_] = ai; obase[N_] = ao;
  }
  __syncthreads();
  if (tid <= N_) { iOff_g[tid] = ibase[tid]; oOff_g[tid] = obase[tid]; }
  for (int e = tid; e < EP_; e += blockDim.x) {
    int s = esrc[e], d = edst[e];
    int pi = ibase[d] + atomicAdd(&ifill[d], 1);
    iSrc_g[pi] = s;
    int po = obase[s] + atomicAdd(&ofill[s], 1);
    oDst_g[po] = d;
  }
}

// ---- K1: proj + bf16 transposed stage via LDS (coalesced stores) ---------------
// grid = 1024 (b = bid&7 XCD-pinned, n, t-half), block 256, 3 blocks/CU.
// Reads x with wave-contiguous 256-B scalar streams; two 128-t rounds; each
// round fills an LDS bf16 tile [128c][128t] then stores 4-KB [c][t16] chunks
// fully coalesced into xs[b][tc][n][c][t16].
__global__ __launch_bounds__(256, 3)
void proj_kernel(const float* __restrict__ x,
                 const float* __restrict__ wa_g,
                 float* __restrict__ a_ws,
                 unsigned short* __restrict__ xs) {
  __shared__ float wal[C_ * 8];                     // 4 KB
  __shared__ unsigned short tile[C_ * TSTRIDE];     // 34 KB
  __shared__ float scr[8 * 128];                    // 4 KB
  const int tid = threadIdx.x;
  const int bid = blockIdx.x;
  const int b = bid & 7;
  const int n = (bid >> 3) & 63;
  const int th = bid >> 9;

  for (int i = tid; i < C_ * 8; i += 256) wal[i] = wa_g[i];
  __syncthreads();

  const int ch = tid >> 7;        // c-half
  const int tl = tid & 127;       // t-local

  for (int r = 0; r < 2; ++r) {
    const int tbase = th * 256 + r * 128;
    const float* xp = x + ((size_t)(b * C_ + ch * 64) * N_ + n) * T_ + tbase + tl;
    float acc[8] = {0.f,0.f,0.f,0.f,0.f,0.f,0.f,0.f};
#pragma unroll 16
    for (int k = 0; k < 64; ++k) {
      const int c = ch * 64 + k;
      float v = xp[(size_t)k * NT_];
      tile[c * TSTRIDE + tl] = f2bf(v);
      const float* w8 = &wal[c * 8];
      acc[0] = fmaf(v, w8[0], acc[0]); acc[1] = fmaf(v, w8[1], acc[1]);
      acc[2] = fmaf(v, w8[2], acc[2]); acc[3] = fmaf(v, w8[3], acc[3]);
      acc[4] = fmaf(v, w8[4], acc[4]); acc[5] = fmaf(v, w8[5], acc[5]);
      acc[6] = fmaf(v, w8[6], acc[6]); acc[7] = fmaf(v, w8[7], acc[7]);
    }
    if (ch == 1) {
#pragma unroll
      for (int j = 0; j < 8; ++j) scr[j * 128 + tl] = acc[j];
    }
    __syncthreads();   // scr + tile complete
    if (ch == 0) {
      size_t abase = ((size_t)(b * N_ + n) * 8) * T_ + tbase + tl;
#pragma unroll
      for (int j = 0; j < 8; ++j)
        a_ws[abase + (size_t)j * T_] = acc[j] + scr[j * 128 + tl];
    }
    // store tile -> xs[b][tc][n][c][t16]; 8 tcs x 4-KB contiguous chunks
    {
      const int tcl = tid >> 5;       // 0..7
      const int sub = tid & 31;
      const int tcg = th * 16 + r * 8 + tcl;
      unsigned short* dst0 = xs + (((size_t)(b * 32 + tcg) * 64 + n) * 128) * 16;
#pragma unroll
      for (int cc = 0; cc < 4; ++cc) {
        const int c = cc * 32 + sub;   // 32 lanes -> 1 KB contiguous dest
        const uint4* src = reinterpret_cast<const uint4*>(
            &tile[c * TSTRIDE + tcl * 16]);
        uint4* dst = reinterpret_cast<uint4*>(dst0 + c * 16);
        dst[0] = src[0];
        dst[1] = src[1];
      }
    }
    __syncthreads();   // tile reusable next round
  }
}

// ---- K2: softmax + aggregation (contiguous bf16 chunks) + epilogue -------------
// grid = 256 (b = bid&7, tc = bid>>3), block 512, 1 block/CU.
__global__ __launch_bounds__(512, 1)
void agg_kernel(const unsigned short* __restrict__ xs,
                const float* __restrict__ a_ws,
                const float* __restrict__ Wm,
                const int* __restrict__ iOff_g, const int* __restrict__ iSrc_g,
                const int* __restrict__ oOff_g, const int* __restrict__ oDst_g,
                const float* __restrict__ bias,
                const float* __restrict__ bn_gamma,
                const float* __restrict__ bn_beta,
                const float* __restrict__ bn_mean,
                const float* __restrict__ bn_var,
                float* __restrict__ out) {
  __shared__ __align__(16) char arena[146432];
  float* a_l  = (float*)arena;                      // [8j][64n][20] 40960 B
  float* z_l  = (float*)(arena + 40960);            // [64nd][16t][4h] 16 KB
  float* w_l  = (float*)(arena + 57344);            // [n*64 + h*16 + t] 16 KB
  int* iSrc   = (int*)(arena + 73728);
  int* oDst   = iSrc + EP_;
  int* iOff   = oDst + EP_;
  int* oOff   = iOff + (N_ + 1);
  unsigned short* xst = (unsigned short*)(arena + 77824);  // [8n][128c][16t] 32 KB
  float* y_l  = (float*)(arena + 110592);           // [4h][128c][17] 34816 B

  const int tid = threadIdx.x;
  const int b  = blockIdx.x & 7;
  const int tc = blockIdx.x >> 3;
  const int t0 = tc * 16;

  if (tid < EP_) { iSrc[tid] = iSrc_g[tid]; oDst[tid] = oDst_g[tid]; }
  else if (tid < EP_ + N_ + 1) {
    int i = tid - EP_;
    iOff[i] = iOff_g[i]; oOff[i] = oOff_g[i];
  }
  {  // a_l load: 512 rows (n,j) of 16 floats
    int n = tid >> 3, j = tid & 7;
    const float4* src = reinterpret_cast<const float4*>(
        a_ws + (((size_t)b * N_ + n) * 8 + j) * T_ + t0);
    float4* dst = reinterpret_cast<float4*>(&a_l[j * 1280 + n * 20]);
    dst[0] = src[0]; dst[1] = src[1]; dst[2] = src[2]; dst[3] = src[3];
  }
  __syncthreads();

  // softmax B: per (dst,t): z = exp(-m)/(den*N)
  {
    const int t = tid & 15, g = tid >> 4;
#pragma unroll
    for (int rep = 0; rep < 2; ++rep) {
      int nd = g + rep * 32;
      int e0 = iOff[nd], e1 = iOff[nd + 1];
      float ad0 = a_l[4 * 1280 + nd * 20 + t];
      float ad1 = a_l[5 * 1280 + nd * 20 + t];
      float ad2 = a_l[6 * 1280 + nd * 20 + t];
      float ad3 = a_l[7 * 1280 + nd * 20 + t];
      float m0 = -1e30f, m1 = -1e30f, m2 = -1e30f, m3 = -1e30f;
      for (int e = e0; e < e1; ++e) {
        int s = iSrc[e];
        float v0 = a_l[0 * 1280 + s * 20 + t] + ad0; v0 = v0 > 0.f ? v0 : NEG_SLOPE * v0;
        float v1 = a_l[1 * 1280 + s * 20 + t] + ad1; v1 = v1 > 0.f ? v1 : NEG_SLOPE * v1;
        float v2 = a_l[2 * 1280 + s * 20 + t] + ad2; v2 = v2 > 0.f ? v2 : NEG_SLOPE * v2;
        float v3 = a_l[3 * 1280 + s * 20 + t] + ad3; v3 = v3 > 0.f ? v3 : NEG_SLOPE * v3;
        m0 = fmaxf(m0, v0); m1 = fmaxf(m1, v1);
        m2 = fmaxf(m2, v2); m3 = fmaxf(m3, v3);
      }
      float d0 = 0.f, d1 = 0.f, d2 = 0.f, d3 = 0.f;
      for (int e = e0; e < e1; ++e) {
        int s = iSrc[e];
        float v0 = a_l[0 * 1280 + s * 20 + t] + ad0; v0 = v0 > 0.f ? v0 : NEG_SLOPE * v0;
        float v1 = a_l[1 * 1280 + s * 20 + t] + ad1; v1 = v1 > 0.f ? v1 : NEG_SLOPE * v1;
        float v2 = a_l[2 * 1280 + s * 20 + t] + ad2; v2 = v2 > 0.f ? v2 : NEG_SLOPE * v2;
        float v3 = a_l[3 * 1280 + s * 20 + t] + ad3; v3 = v3 > 0.f ? v3 : NEG_SLOPE * v3;
        d0 += __expf(v0 - m0); d1 += __expf(v1 - m1);
        d2 += __expf(v2 - m2); d3 += __expf(v3 - m3);
      }
      float4 zv;
      zv.x = __expf(-m0) / (d0 * (float)N_);
      zv.y = __expf(-m1) / (d1 * (float)N_);
      zv.z = __expf(-m2) / (d2 * (float)N_);
      zv.w = __expf(-m3) / (d3 * (float)N_);
      *reinterpret_cast<float4*>(&z_l[(nd * 16 + t) * 4]) = zv;
    }
  }
  __syncthreads();

  // softmax C: per (src,t) gather -> w_l[n*64 + h*16 + t]
  {
    const int t = tid & 15, g = tid >> 4;
#pragma unroll
    for (int rep = 0; rep < 2; ++rep) {
      int src = g + rep * 32;
      int e0 = oOff[src], e1 = oOff[src + 1];
      float as0 = a_l[0 * 1280 + src * 20 + t];
      float as1 = a_l[1 * 1280 + src * 20 + t];
      float as2 = a_l[2 * 1280 + src * 20 + t];
      float as3 = a_l[3 * 1280 + src * 20 + t];
      float w0 = 0.f, w1 = 0.f, w2 = 0.f, w3 = 0.f;
      for (int e = e0; e < e1; ++e) {
        int d = oDst[e];
        float4 zv = *reinterpret_cast<const float4*>(&z_l[(d * 16 + t) * 4]);
        float v0 = as0 + a_l[4 * 1280 + d * 20 + t]; v0 = v0 > 0.f ? v0 : NEG_SLOPE * v0;
        float v1 = as1 + a_l[5 * 1280 + d * 20 + t]; v1 = v1 > 0.f ? v1 : NEG_SLOPE * v1;
        float v2 = as2 + a_l[6 * 1280 + d * 20 + t]; v2 = v2 > 0.f ? v2 : NEG_SLOPE * v2;
        float v3 = as3 + a_l[7 * 1280 + d * 20 + t]; v3 = v3 > 0.f ? v3 : NEG_SLOPE * v3;
        w0 += __expf(v0) * zv.x;
        w1 += __expf(v1) * zv.y;
        w2 += __expf(v2) * zv.z;
        w3 += __expf(v3) * zv.w;
      }
      w_l[src * 64 +  0 + t] = w0;
      w_l[src * 64 + 16 + t] = w1;
      w_l[src * 64 + 32 + t] = w2;
      w_l[src * 64 + 48 + t] = w3;
    }
  }
  __syncthreads();

  // aggregation: y[c][h][4t] in registers over 8 chunks of 8 n
  const int cA = tid >> 2;            // c 0..127
  const int tq = tid & 3;             // t-quad
  float4 yA[4];
#pragma unroll
  for (int h = 0; h < 4; ++h) { yA[h].x = 0.f; yA[h].y = 0.f; yA[h].z = 0.f; yA[h].w = 0.f; }
  const uint4* xtile = reinterpret_cast<const uint4*>(
      xs + ((size_t)(b * 32 + tc) * 64 * 128) * 16);

  for (int o = 0; o < 8; ++o) {
    {  // stage [8n][128c][16t] chunk (32 KB contiguous)
      const uint4* src = xtile + (size_t)o * 2048;
      uint4* dst = reinterpret_cast<uint4*>(xst);
#pragma unroll
      for (int i = 0; i < 4; ++i) dst[tid + 512 * i] = src[tid + 512 * i];
    }
    __syncthreads();
#pragma unroll
    for (int n8 = 0; n8 < 8; ++n8) {
      const int n = o * 8 + n8;
      ushort4 xv = *reinterpret_cast<const ushort4*>(
          &xst[n8 * 2048 + cA * 16 + tq * 4]);
      float x0 = bf2f(xv.x), x1 = bf2f(xv.y), x2 = bf2f(xv.z), x3 = bf2f(xv.w);
#pragma unroll
      for (int h = 0; h < 4; ++h) {
        float4 wv = *reinterpret_cast<const float4*>(&w_l[n * 64 + h * 16 + tq * 4]);
        yA[h].x = fmaf(x0, wv.x, yA[h].x);
        yA[h].y = fmaf(x1, wv.y, yA[h].y);
        yA[h].z = fmaf(x2, wv.z, yA[h].z);
        yA[h].w = fmaf(x3, wv.w, yA[h].w);
      }
    }
    __syncthreads();
  }
#pragma unroll
  for (int h = 0; h < 4; ++h) {
    y_l[h * 2176 + cA * 17 + tq * 4 + 0] = yA[h].x;
    y_l[h * 2176 + cA * 17 + tq * 4 + 1] = yA[h].y;
    y_l[h * 2176 + cA * 17 + tq * 4 + 2] = yA[h].z;
    y_l[h * 2176 + cA * 17 + tq * 4 + 3] = yA[h].w;
  }
  __syncthreads();

  // epilogue: out[oc][t] = BN(sum_c y[h][c][t]*W[c][h][d] + bias)
  {
    const int h4 = tid >> 7;            // head
    const int dp = (tid >> 4) & 7;      // d-group (4 d's)
    const int te = tid & 15;
    float oacc[4] = {0.f, 0.f, 0.f, 0.f};
#pragma unroll 4
    for (int c = 0; c < C_; ++c) {
      float yv = y_l[h4 * 2176 + c * 17 + te];
      const float4 wv = *reinterpret_cast<const float4*>(
          &Wm[((size_t)c * H_ + h4) * D_ + dp * 4]);
      oacc[0] = fmaf(yv, wv.x, oacc[0]);
      oacc[1] = fmaf(yv, wv.y, oacc[1]);
      oacc[2] = fmaf(yv, wv.z, oacc[2]);
      oacc[3] = fmaf(yv, wv.w, oacc[3]);
    }
#pragma unroll
    for (int k = 0; k < 4; ++k) {
      int oc = h4 * D_ + dp * 4 + k;
      float scale = bn_gamma[oc] * rsqrtf(bn_var[oc] + BN_EPS);
      float shift = bn_beta[oc] - bn_mean[oc] * scale;
      out[((size_t)b * OUT_ + oc) * T_ + t0 + te] =
          (oacc[k] + bias[oc]) * scale + shift;
    }
  }
}

extern "C" void kernel_launch(void* const* d_in, const int* in_sizes, int n_in,
                              void* d_out, int out_size, void* d_ws, size_t ws_size,
                              hipStream_t stream) {
  const float* x        = (const float*)d_in[0];
  const float* W        = (const float*)d_in[1];
  const float* att_src  = (const float*)d_in[2];
  const float* att_dst  = (const float*)d_in[3];
  const float* bias     = (const float*)d_in[4];
  const float* bn_gamma = (const float*)d_in[5];
  const float* bn_beta  = (const float*)d_in[6];
  const float* bn_mean  = (const float*)d_in[7];
  const float* bn_var   = (const float*)d_in[8];
  const int* edge_index = (const int*)d_in[9];
  float* out = (float*)d_out;

  char* ws = (char*)d_ws;
  float* wa   = (float*)ws;            // 4 KB
  int* iOff_g = (int*)(ws + 4096);
  int* iSrc_g = (int*)(ws + 4608);
  int* oOff_g = (int*)(ws + 6144);
  int* oDst_g = (int*)(ws + 6656);
  float* a_ws = (float*)(ws + 16384);                             // 8 MB [b][n][j][t]
  unsigned short* xs = (unsigned short*)(ws + 16384 + (size_t)8 * 1024 * 1024);  // 64 MB bf16 [b][tc][n][c][t16]

  setup_kernel<<<1, 256, 0, stream>>>(W, att_src, att_dst, edge_index, wa,
                                      iOff_g, iSrc_g, oOff_g, oDst_g);
  proj_kernel<<<1024, 256, 0, stream>>>(x, wa, a_ws, xs);
  agg_kernel<<<256, 512, 0, stream>>>(xs, a_ws, W, iOff_g, iSrc_g, oOff_g, oDst_g,
                                      bias, bn_gamma, bn_beta, bn_mean, bn_var,
                                      out);
}

// Round 14
// 89.168 us; speedup vs baseline: 1.5498x; 1.5498x over previous
//
#include <hip/hip_runtime.h>
#include <math.h>

#define B_ 8
#define C_ 128
#define N_ 64
#define T_ 512
#define H_ 4
#define D_ 32
#define OUT_ 128
#define E_ 256
#define EP_ 320   // E + N self-loops
#define NEG_SLOPE 0.2f
#define BN_EPS 1e-5f
#define NT_ (N_ * T_)
#define TSTRIDE 136   // tile row stride in shorts (272 B, 16B-aligned)

__device__ inline unsigned short f2bf(float f) {   // RNE float->bf16
  unsigned u = __float_as_uint(f);
  u += 0x7FFFu + ((u >> 16) & 1u);
  return (unsigned short)(u >> 16);
}
__device__ inline float bf2f(unsigned short s) {
  return __uint_as_float(((unsigned)s) << 16);
}

// ---- setup: wa[c][8] = W·att; in-list (src per in-edge, grouped by dst);
// ----        out-list (dst per out-edge, grouped by src)
__global__ void setup_kernel(const float* __restrict__ W,
                             const float* __restrict__ att_src,
                             const float* __restrict__ att_dst,
                             const int* __restrict__ edge_index,
                             float* __restrict__ wa,
                             int* __restrict__ iOff_g, int* __restrict__ iSrc_g,
                             int* __restrict__ oOff_g, int* __restrict__ oDst_g) {
  __shared__ int icnt[N_], ibase[N_ + 1], ifill[N_];
  __shared__ int ocnt[N_], obase[N_ + 1], ofill[N_];
  __shared__ int esrc[EP_], edst[EP_];
  int tid = threadIdx.x;

  for (int idx = tid; idx < C_ * 8; idx += blockDim.x) {
    int c = idx >> 3, j = idx & 7, h = j & 3;
    const float* att = (j < 4) ? att_src : att_dst;
    float s = 0.f;
    for (int d = 0; d < D_; ++d)
      s += W[(c * H_ + h) * D_ + d] * att[h * D_ + d];
    wa[idx] = s;
  }
  if (tid < N_) { icnt[tid] = 0; ifill[tid] = 0; ocnt[tid] = 0; ofill[tid] = 0; }
  __syncthreads();
  for (int e = tid; e < EP_; e += blockDim.x) {
    int s, d;
    if (e < E_) { s = edge_index[e]; d = edge_index[E_ + e]; }
    else        { s = e - E_;        d = e - E_; }
    esrc[e] = s; edst[e] = d;
    atomicAdd(&icnt[d], 1);
    atomicAdd(&ocnt[s], 1);
  }
  __syncthreads();
  if (tid == 0) {
    int ai = 0, ao = 0;
    for (int n = 0; n < N_; ++n) {
      ibase[n] = ai; ai += icnt[n];
      obase[n] = ao; ao += ocnt[n];
    }
    ibase[N_] = ai; obase[N_] = ao;
  }
  __syncthreads();
  if (tid <= N_) { iOff_g[tid] = ibase[tid]; oOff_g[tid] = obase[tid]; }
  for (int e = tid; e < EP_; e += blockDim.x) {
    int s = esrc[e], d = edst[e];
    int pi = ibase[d] + atomicAdd(&ifill[d], 1);
    iSrc_g[pi] = s;
    int po = obase[s] + atomicAdd(&ofill[s], 1);
    oDst_g[po] = d;
  }
}

// ---- K1: proj + bf16 transposed stage, float4 reads + coalesced stores ---------
// grid = 2048 (b = bid&7, n, t-quarter), block 256, 2 blocks/CU.
// Thread (c-oct, t-quad): 2 batches of 8 float4 loads (128 B/lane in flight),
// bf16 -> LDS tile [128c][128t]; a-partials in regs; LDS oct-reduce for a;
// coalesced 1-KB wave stores into xs[b][tc][n][c][t16].
__global__ __launch_bounds__(256, 2)
void proj_kernel(const float* __restrict__ x,
                 const float* __restrict__ wa_g,
                 float* __restrict__ a_ws,
                 unsigned short* __restrict__ xs) {
  __shared__ float wal[C_ * 8];                     // 4 KB
  __shared__ unsigned short tile[C_ * TSTRIDE];     // 34 KB
  __shared__ float scr[8 * 8 * 128];                // [oct][j][t] 32 KB
  const int tid = threadIdx.x;
  const int bid = blockIdx.x;
  const int b  = bid & 7;
  const int n  = (bid >> 3) & 63;
  const int th = bid >> 9;                          // t-quarter 0..3
  const int tbase = th * 128;

  for (int i = tid; i < C_ * 8; i += 256) wal[i] = wa_g[i];
  __syncthreads();

  const int oct = tid >> 5;       // c-octant 0..7
  const int tq  = tid & 31;       // t-quad: t = tq*4 .. +3
  const float* xp = x + ((size_t)(b * C_ + oct) * N_ + n) * T_ + tbase + tq * 4;

  float4 acc[8];
#pragma unroll
  for (int j = 0; j < 8; ++j) { acc[j].x = 0.f; acc[j].y = 0.f; acc[j].z = 0.f; acc[j].w = 0.f; }

#pragma unroll
  for (int half = 0; half < 2; ++half) {
    float4 xv[8];
#pragma unroll
    for (int u = 0; u < 8; ++u)
      xv[u] = *reinterpret_cast<const float4*>(xp + (size_t)(half * 8 + u) * 8 * NT_);
#pragma unroll
    for (int u = 0; u < 8; ++u) {
      const int c = oct + (half * 8 + u) * 8;
      ushort4 s;
      s.x = f2bf(xv[u].x); s.y = f2bf(xv[u].y);
      s.z = f2bf(xv[u].z); s.w = f2bf(xv[u].w);
      *reinterpret_cast<ushort4*>(&tile[c * TSTRIDE + tq * 4]) = s;
      const float4 w0 = *reinterpret_cast<const float4*>(&wal[c * 8]);
      const float4 w1 = *reinterpret_cast<const float4*>(&wal[c * 8 + 4]);
      acc[0].x = fmaf(xv[u].x, w0.x, acc[0].x); acc[0].y = fmaf(xv[u].y, w0.x, acc[0].y);
      acc[0].z = fmaf(xv[u].z, w0.x, acc[0].z); acc[0].w = fmaf(xv[u].w, w0.x, acc[0].w);
      acc[1].x = fmaf(xv[u].x, w0.y, acc[1].x); acc[1].y = fmaf(xv[u].y, w0.y, acc[1].y);
      acc[1].z = fmaf(xv[u].z, w0.y, acc[1].z); acc[1].w = fmaf(xv[u].w, w0.y, acc[1].w);
      acc[2].x = fmaf(xv[u].x, w0.z, acc[2].x); acc[2].y = fmaf(xv[u].y, w0.z, acc[2].y);
      acc[2].z = fmaf(xv[u].z, w0.z, acc[2].z); acc[2].w = fmaf(xv[u].w, w0.z, acc[2].w);
      acc[3].x = fmaf(xv[u].x, w0.w, acc[3].x); acc[3].y = fmaf(xv[u].y, w0.w, acc[3].y);
      acc[3].z = fmaf(xv[u].z, w0.w, acc[3].z); acc[3].w = fmaf(xv[u].w, w0.w, acc[3].w);
      acc[4].x = fmaf(xv[u].x, w1.x, acc[4].x); acc[4].y = fmaf(xv[u].y, w1.x, acc[4].y);
      acc[4].z = fmaf(xv[u].z, w1.x, acc[4].z); acc[4].w = fmaf(xv[u].w, w1.x, acc[4].w);
      acc[5].x = fmaf(xv[u].x, w1.y, acc[5].x); acc[5].y = fmaf(xv[u].y, w1.y, acc[5].y);
      acc[5].z = fmaf(xv[u].z, w1.y, acc[5].z); acc[5].w = fmaf(xv[u].w, w1.y, acc[5].w);
      acc[6].x = fmaf(xv[u].x, w1.z, acc[6].x); acc[6].y = fmaf(xv[u].y, w1.z, acc[6].y);
      acc[6].z = fmaf(xv[u].z, w1.z, acc[6].z); acc[6].w = fmaf(xv[u].w, w1.z, acc[6].w);
      acc[7].x = fmaf(xv[u].x, w1.w, acc[7].x); acc[7].y = fmaf(xv[u].y, w1.w, acc[7].y);
      acc[7].z = fmaf(xv[u].z, w1.w, acc[7].z); acc[7].w = fmaf(xv[u].w, w1.w, acc[7].w);
    }
  }
#pragma unroll
  for (int j = 0; j < 8; ++j)
    *reinterpret_cast<float4*>(&scr[(oct * 8 + j) * 128 + tq * 4]) = acc[j];
  __syncthreads();

  // a oct-reduce + store: thread (j = tid>>5, tq2 = tid&31)
  {
    const int j = tid >> 5, tq2 = tid & 31;
    float4 r = {0.f, 0.f, 0.f, 0.f};
#pragma unroll
    for (int o = 0; o < 8; ++o) {
      float4 v = *reinterpret_cast<const float4*>(&scr[(o * 8 + j) * 128 + tq2 * 4]);
      r.x += v.x; r.y += v.y; r.z += v.z; r.w += v.w;
    }
    *reinterpret_cast<float4*>(
        a_ws + ((size_t)(b * N_ + n) * 8 + j) * T_ + tbase + tq2 * 4) = r;
  }

  // tile -> xs[b][tc][n][c][t16]: 8 tcs x 1-KB contiguous wave chunks
  {
    const int tcl = tid >> 5;       // 0..7
    const int sub = tid & 31;
    const int tcg = th * 8 + tcl;
    unsigned short* dst0 = xs + (((size_t)(b * 32 + tcg) * 64 + n) * 128) * 16;
#pragma unroll
    for (int cc = 0; cc < 4; ++cc) {
      const int c = cc * 32 + sub;   // 32 lanes -> 1 KB contiguous dest
      const uint4* src = reinterpret_cast<const uint4*>(&tile[c * TSTRIDE + tcl * 16]);
      uint4* dst = reinterpret_cast<uint4*>(dst0 + c * 16);
      dst[0] = src[0];
      dst[1] = src[1];
    }
  }
}

// ---- K2: softmax + aggregation (contiguous bf16 chunks) + epilogue -------------
// grid = 256 (b = bid&7, tc = bid>>3), block 512, 1 block/CU.  [r13-verified]
__global__ __launch_bounds__(512, 1)
void agg_kernel(const unsigned short* __restrict__ xs,
                const float* __restrict__ a_ws,
                const float* __restrict__ Wm,
                const int* __restrict__ iOff_g, const int* __restrict__ iSrc_g,
                const int* __restrict__ oOff_g, const int* __restrict__ oDst_g,
                const float* __restrict__ bias,
                const float* __restrict__ bn_gamma,
                const float* __restrict__ bn_beta,
                const float* __restrict__ bn_mean,
                const float* __restrict__ bn_var,
                float* __restrict__ out) {
  __shared__ __align__(16) char arena[146432];
  float* a_l  = (float*)arena;                      // [8j][64n][20] 40960 B
  float* z_l  = (float*)(arena + 40960);            // [64nd][16t][4h] 16 KB
  float* w_l  = (float*)(arena + 57344);            // [n*64 + h*16 + t] 16 KB
  int* iSrc   = (int*)(arena + 73728);
  int* oDst   = iSrc + EP_;
  int* iOff   = oDst + EP_;
  int* oOff   = iOff + (N_ + 1);
  unsigned short* xst = (unsigned short*)(arena + 77824);  // [8n][128c][16t] 32 KB
  float* y_l  = (float*)(arena + 110592);           // [4h][128c][17] 34816 B

  const int tid = threadIdx.x;
  const int b  = blockIdx.x & 7;
  const int tc = blockIdx.x >> 3;
  const int t0 = tc * 16;

  if (tid < EP_) { iSrc[tid] = iSrc_g[tid]; oDst[tid] = oDst_g[tid]; }
  else if (tid < EP_ + N_ + 1) {
    int i = tid - EP_;
    iOff[i] = iOff_g[i]; oOff[i] = oOff_g[i];
  }
  {  // a_l load: 512 rows (n,j) of 16 floats
    int n = tid >> 3, j = tid & 7;
    const float4* src = reinterpret_cast<const float4*>(
        a_ws + (((size_t)b * N_ + n) * 8 + j) * T_ + t0);
    float4* dst = reinterpret_cast<float4*>(&a_l[j * 1280 + n * 20]);
    dst[0] = src[0]; dst[1] = src[1]; dst[2] = src[2]; dst[3] = src[3];
  }
  __syncthreads();

  // softmax B: per (dst,t): z = exp(-m)/(den*N)
  {
    const int t = tid & 15, g = tid >> 4;
#pragma unroll
    for (int rep = 0; rep < 2; ++rep) {
      int nd = g + rep * 32;
      int e0 = iOff[nd], e1 = iOff[nd + 1];
      float ad0 = a_l[4 * 1280 + nd * 20 + t];
      float ad1 = a_l[5 * 1280 + nd * 20 + t];
      float ad2 = a_l[6 * 1280 + nd * 20 + t];
      float ad3 = a_l[7 * 1280 + nd * 20 + t];
      float m0 = -1e30f, m1 = -1e30f, m2 = -1e30f, m3 = -1e30f;
      for (int e = e0; e < e1; ++e) {
        int s = iSrc[e];
        float v0 = a_l[0 * 1280 + s * 20 + t] + ad0; v0 = v0 > 0.f ? v0 : NEG_SLOPE * v0;
        float v1 = a_l[1 * 1280 + s * 20 + t] + ad1; v1 = v1 > 0.f ? v1 : NEG_SLOPE * v1;
        float v2 = a_l[2 * 1280 + s * 20 + t] + ad2; v2 = v2 > 0.f ? v2 : NEG_SLOPE * v2;
        float v3 = a_l[3 * 1280 + s * 20 + t] + ad3; v3 = v3 > 0.f ? v3 : NEG_SLOPE * v3;
        m0 = fmaxf(m0, v0); m1 = fmaxf(m1, v1);
        m2 = fmaxf(m2, v2); m3 = fmaxf(m3, v3);
      }
      float d0 = 0.f, d1 = 0.f, d2 = 0.f, d3 = 0.f;
      for (int e = e0; e < e1; ++e) {
        int s = iSrc[e];
        float v0 = a_l[0 * 1280 + s * 20 + t] + ad0; v0 = v0 > 0.f ? v0 : NEG_SLOPE * v0;
        float v1 = a_l[1 * 1280 + s * 20 + t] + ad1; v1 = v1 > 0.f ? v1 : NEG_SLOPE * v1;
        float v2 = a_l[2 * 1280 + s * 20 + t] + ad2; v2 = v2 > 0.f ? v2 : NEG_SLOPE * v2;
        float v3 = a_l[3 * 1280 + s * 20 + t] + ad3; v3 = v3 > 0.f ? v3 : NEG_SLOPE * v3;
        d0 += __expf(v0 - m0); d1 += __expf(v1 - m1);
        d2 += __expf(v2 - m2); d3 += __expf(v3 - m3);
      }
      float4 zv;
      zv.x = __expf(-m0) / (d0 * (float)N_);
      zv.y = __expf(-m1) / (d1 * (float)N_);
      zv.z = __expf(-m2) / (d2 * (float)N_);
      zv.w = __expf(-m3) / (d3 * (float)N_);
      *reinterpret_cast<float4*>(&z_l[(nd * 16 + t) * 4]) = zv;
    }
  }
  __syncthreads();

  // softmax C: per (src,t) gather -> w_l[n*64 + h*16 + t]
  {
    const int t = tid & 15, g = tid >> 4;
#pragma unroll
    for (int rep = 0; rep < 2; ++rep) {
      int src = g + rep * 32;
      int e0 = oOff[src], e1 = oOff[src + 1];
      float as0 = a_l[0 * 1280 + src * 20 + t];
      float as1 = a_l[1 * 1280 + src * 20 + t];
      float as2 = a_l[2 * 1280 + src * 20 + t];
      float as3 = a_l[3 * 1280 + src * 20 + t];
      float w0 = 0.f, w1 = 0.f, w2 = 0.f, w3 = 0.f;
      for (int e = e0; e < e1; ++e) {
        int d = oDst[e];
        float4 zv = *reinterpret_cast<const float4*>(&z_l[(d * 16 + t) * 4]);
        float v0 = as0 + a_l[4 * 1280 + d * 20 + t]; v0 = v0 > 0.f ? v0 : NEG_SLOPE * v0;
        float v1 = as1 + a_l[5 * 1280 + d * 20 + t]; v1 = v1 > 0.f ? v1 : NEG_SLOPE * v1;
        float v2 = as2 + a_l[6 * 1280 + d * 20 + t]; v2 = v2 > 0.f ? v2 : NEG_SLOPE * v2;
        float v3 = as3 + a_l[7 * 1280 + d * 20 + t]; v3 = v3 > 0.f ? v3 : NEG_SLOPE * v3;
        w0 += __expf(v0) * zv.x;
        w1 += __expf(v1) * zv.y;
        w2 += __expf(v2) * zv.z;
        w3 += __expf(v3) * zv.w;
      }
      w_l[src * 64 +  0 + t] = w0;
      w_l[src * 64 + 16 + t] = w1;
      w_l[src * 64 + 32 + t] = w2;
      w_l[src * 64 + 48 + t] = w3;
    }
  }
  __syncthreads();

  // aggregation: y[c][h][4t] in registers over 8 chunks of 8 n
  const int cA = tid >> 2;            // c 0..127
  const int tq = tid & 3;             // t-quad
  float4 yA[4];
#pragma unroll
  for (int h = 0; h < 4; ++h) { yA[h].x = 0.f; yA[h].y = 0.f; yA[h].z = 0.f; yA[h].w = 0.f; }
  const uint4* xtile = reinterpret_cast<const uint4*>(
      xs + ((size_t)(b * 32 + tc) * 64 * 128) * 16);

  for (int o = 0; o < 8; ++o) {
    {  // stage [8n][128c][16t] chunk (32 KB contiguous)
      const uint4* src = xtile + (size_t)o * 2048;
      uint4* dst = reinterpret_cast<uint4*>(xst);
#pragma unroll
      for (int i = 0; i < 4; ++i) dst[tid + 512 * i] = src[tid + 512 * i];
    }
    __syncthreads();
#pragma unroll
    for (int n8 = 0; n8 < 8; ++n8) {
      const int n = o * 8 + n8;
      ushort4 xv = *reinterpret_cast<const ushort4*>(
          &xst[n8 * 2048 + cA * 16 + tq * 4]);
      float x0 = bf2f(xv.x), x1 = bf2f(xv.y), x2 = bf2f(xv.z), x3 = bf2f(xv.w);
#pragma unroll
      for (int h = 0; h < 4; ++h) {
        float4 wv = *reinterpret_cast<const float4*>(&w_l[n * 64 + h * 16 + tq * 4]);
        yA[h].x = fmaf(x0, wv.x, yA[h].x);
        yA[h].y = fmaf(x1, wv.y, yA[h].y);
        yA[h].z = fmaf(x2, wv.z, yA[h].z);
        yA[h].w = fmaf(x3, wv.w, yA[h].w);
      }
    }
    __syncthreads();
  }
#pragma unroll
  for (int h = 0; h < 4; ++h) {
    y_l[h * 2176 + cA * 17 + tq * 4 + 0] = yA[h].x;
    y_l[h * 2176 + cA * 17 + tq * 4 + 1] = yA[h].y;
    y_l[h * 2176 + cA * 17 + tq * 4 + 2] = yA[h].z;
    y_l[h * 2176 + cA * 17 + tq * 4 + 3] = yA[h].w;
  }
  __syncthreads();

  // epilogue: out[oc][t] = BN(sum_c y[h][c][t]*W[c][h][d] + bias)
  {
    const int h4 = tid >> 7;            // head
    const int dp = (tid >> 4) & 7;      // d-group (4 d's)
    const int te = tid & 15;
    float oacc[4] = {0.f, 0.f, 0.f, 0.f};
#pragma unroll 4
    for (int c = 0; c < C_; ++c) {
      float yv = y_l[h4 * 2176 + c * 17 + te];
      const float4 wv = *reinterpret_cast<const float4*>(
          &Wm[((size_t)c * H_ + h4) * D_ + dp * 4]);
      oacc[0] = fmaf(yv, wv.x, oacc[0]);
      oacc[1] = fmaf(yv, wv.y, oacc[1]);
      oacc[2] = fmaf(yv, wv.z, oacc[2]);
      oacc[3] = fmaf(yv, wv.w, oacc[3]);
    }
#pragma unroll
    for (int k = 0; k < 4; ++k) {
      int oc = h4 * D_ + dp * 4 + k;
      float scale = bn_gamma[oc] * rsqrtf(bn_var[oc] + BN_EPS);
      float shift = bn_beta[oc] - bn_mean[oc] * scale;
      out[((size_t)b * OUT_ + oc) * T_ + t0 + te] =
          (oacc[k] + bias[oc]) * scale + shift;
    }
  }
}

extern "C" void kernel_launch(void* const* d_in, const int* in_sizes, int n_in,
                              void* d_out, int out_size, void* d_ws, size_t ws_size,
                              hipStream_t stream) {
  const float* x        = (const float*)d_in[0];
  const float* W        = (const float*)d_in[1];
  const float* att_src  = (const float*)d_in[2];
  const float* att_dst  = (const float*)d_in[3];
  const float* bias     = (const float*)d_in[4];
  const float* bn_gamma = (const float*)d_in[5];
  const float* bn_beta  = (const float*)d_in[6];
  const float* bn_mean  = (const float*)d_in[7];
  const float* bn_var   = (const float*)d_in[8];
  const int* edge_index = (const int*)d_in[9];
  float* out = (float*)d_out;

  char* ws = (char*)d_ws;
  float* wa   = (float*)ws;            // 4 KB
  int* iOff_g = (int*)(ws + 4096);
  int* iSrc_g = (int*)(ws + 4608);
  int* oOff_g = (int*)(ws + 6144);
  int* oDst_g = (int*)(ws + 6656);
  float* a_ws = (float*)(ws + 16384);                             // 8 MB [b][n][j][t]
  unsigned short* xs = (unsigned short*)(ws + 16384 + (size_t)8 * 1024 * 1024);  // 64 MB bf16 [b][tc][n][c][t16]

  setup_kernel<<<1, 256, 0, stream>>>(W, att_src, att_dst, edge_index, wa,
                                      iOff_g, iSrc_g, oOff_g, oDst_g);
  proj_kernel<<<2048, 256, 0, stream>>>(x, wa, a_ws, xs);
  agg_kernel<<<256, 512, 0, stream>>>(xs, a_ws, W, iOff_g, iSrc_g, oOff_g, oDst_g,
                                      bias, bn_gamma, bn_beta, bn_mean, bn_var,
                                      out);
}